// Round 12
// baseline (295.863 us; speedup 1.0000x reference)
//
#include <hip/hip_runtime.h>

#define NIN 64
#define NOUT 64
#define NTO 16
#define HH 192
#define WW 192
#define HO 190
#define WO 190
#define WBUF 5120            // per-wave buffer: main 18x64 floats (4608B) + halo 18x4 (288B) + pad
#define NBLK 2304            // 36 groups (9 tiles x 4 batch) x 64 out channels

typedef const __attribute__((address_space(1))) void gv_t;
typedef __attribute__((address_space(3))) void lv_t;

__global__ __launch_bounds__(256, 7) void scm_kernel(
    const float* __restrict__ x,
    const float* __restrict__ w,
    const float* __restrict__ bias,
    const int* __restrict__ conn_in,
    float* __restrict__ out)
{
    __shared__ char smem[4 * WBUF];   // 20480 B: 4 waves x single wave-private buffer

    const int tid  = threadIdx.x;
    const int lane = tid & 63;
    const int tx   = tid & 15;       // col group of 4
    const int ty   = tid >> 4;       // row group of 4 (block-wide)
    const int wv   = ty >> 2;        // wave id 0..3 (rows 16*wv .. +15)
    const int lty  = ty & 3;         // row group within wave

    // XCD-aware swizzle (bijective, 2304 % 8 == 0), o-minor for L2 gather reuse.
    const int lid = (blockIdx.x & 7) * (NBLK / 8) + (blockIdx.x >> 3);
    const int o   = lid & 63;
    const int g   = lid >> 6;        // 0..35
    const int tile = g % 9;
    const int b    = g / 9;
    const int i0 = (tile / 3) * 64;
    const int j0 = (tile % 3) * 64;

    // ---- Wave-private LDS layout (5120 B):
    //   [0..4607]    main[18 rows][64 floats] (256 B stride) = global cols j0..j0+63
    //   [4608..4895] halo[18 rows][4 floats]  (16 B stride)  = global cols j0+64..67
    //   [4896..5119] pad (written by halo round 1 overflow, never read)
    // width-4 DMA: lane writes ONE dword -> banks lane%32, 2 lanes/bank = conflict-free.
    // Main round s (0..17) = exactly row s: global (i0+16wv+s, j0+lane), row-clamped.
    // Clamped/garbage slots feed only outputs >= row/col 190 (discarded).
    int goff[20];
    #pragma unroll
    for (int s = 0; s < 18; ++s) {
        int gr = i0 + 16 * wv + s; if (gr > 191) gr = 191;
        goff[s] = (gr * WW + j0 + lane) * 4;
    }
    #pragma unroll
    for (int h = 0; h < 2; ++h) {
        int u = h * 64 + lane;
        int hr = u >> 2;                       // 0..31; >=18 lands in pad
        int gr = i0 + 16 * wv + hr; if (gr > 191) gr = 191;
        int gc = j0 + 64 + (u & 3); if (gc > 191) gc = 191;
        goff[18 + h] = (gr * WW + gc) * 4;
    }

    char* wbase = smem + wv * WBUF;
    // Read offsets (channel-independent):
    //   A = float4 cols 4tx..+3  at main[lr][4tx]
    //   B = float2 cols 4tx+4,+5 = first 8B of main[lr][4tx+4], or halo[lr] for tx=15
    int offA[6], offB[6];
    #pragma unroll
    for (int r = 0; r < 6; ++r) {
        int lr = lty * 4 + r;
        offA[r] = lr * 256 + tx * 16;
        offB[r] = (tx < 15) ? (lr * 256 + (tx + 1) * 16) : (4608 + lr * 16);
    }

    const char* xb = (const char*)x + (size_t)b * NIN * HH * WW * 4;
    const int kbase = o * NTO;

    float acc[4][4];
    #pragma unroll
    for (int i = 0; i < 4; ++i)
        #pragma unroll
        for (int p = 0; p < 4; ++p) acc[i][p] = 0.f;

    #pragma unroll 1
    for (int t = 0; t < NTO; ++t) {
        // Previous-channel ds_reads must retire before overwriting the
        // wave-private buffer. Wave-local, essentially free.
        asm volatile("s_waitcnt lgkmcnt(0)" ::: "memory");
        __builtin_amdgcn_sched_barrier(0);

        const int ci = __builtin_amdgcn_readfirstlane(conn_in[kbase + t]);
        {
            const char* src = xb + (size_t)ci * (HH * WW * 4);
            #pragma unroll
            for (int s = 0; s < 18; ++s)
                __builtin_amdgcn_global_load_lds((gv_t*)(src + goff[s]),
                                                 (lv_t*)(wbase + s * 256),
                                                 4, 0, 0);
            #pragma unroll
            for (int h = 0; h < 2; ++h)
                __builtin_amdgcn_global_load_lds((gv_t*)(src + goff[18 + h]),
                                                 (lv_t*)(wbase + 4608 + h * 256),
                                                 4, 0, 0);
        }

        // Scalar weight loads overlap the DMA wait.
        float wv9[9];
        #pragma unroll
        for (int q = 0; q < 9; ++q) wv9[q] = w[(kbase + t) * 9 + q];

        asm volatile("s_waitcnt vmcnt(0)" ::: "memory");
        __builtin_amdgcn_sched_barrier(0);

        #pragma unroll
        for (int r = 0; r < 6; ++r) {
            const float4 v4 = *(const float4*)(wbase + offA[r]);
            const float2 v2 = *(const float2*)(wbase + offB[r]);
            const float rowv[6] = {v4.x, v4.y, v4.z, v4.w, v2.x, v2.y};
            #pragma unroll
            for (int i = 0; i < 4; ++i) {
                const int kh = r - i;
                if (kh >= 0 && kh < 3) {
                    #pragma unroll
                    for (int kw = 0; kw < 3; ++kw) {
                        const float wk = wv9[kh * 3 + kw];
                        #pragma unroll
                        for (int p = 0; p < 4; ++p)
                            acc[i][p] = fmaf(wk, rowv[p + kw], acc[i][p]);
                    }
                }
            }
        }
    }

    const float bv = bias[o];
    float* outp = out + (size_t)(b * NOUT + o) * (HO * WO);
    #pragma unroll
    for (int i = 0; i < 4; ++i) {
        const int gi = i0 + ty * 4 + i;
        if (gi < HO) {
            const int gj = j0 + tx * 4;
            float* row = outp + (size_t)gi * WO + gj;
            if (gj + 3 < WO) {
                *(float2*)(row)     = make_float2(acc[i][0] + bv, acc[i][1] + bv);
                *(float2*)(row + 2) = make_float2(acc[i][2] + bv, acc[i][3] + bv);
            } else {
                #pragma unroll
                for (int p = 0; p < 4; ++p)
                    if (gj + p < WO) row[p] = acc[i][p] + bv;
            }
        }
    }
}

extern "C" void kernel_launch(void* const* d_in, const int* in_sizes, int n_in,
                              void* d_out, int out_size, void* d_ws, size_t ws_size,
                              hipStream_t stream) {
    const float* x       = (const float*)d_in[0];
    const float* weight  = (const float*)d_in[1];
    const float* bias    = (const float*)d_in[2];
    const int*   conn_in = (const int*)d_in[3];
    // d_in[4] = conn_out (implicit: k -> k/16)

    dim3 grid(NBLK);
    dim3 block(256);
    scm_kernel<<<grid, block, 0, stream>>>(x, weight, bias, conn_in, (float*)d_out);
}

// Round 13
// 78.873 us; speedup vs baseline: 3.7511x; 3.7511x over previous
//
#include <hip/hip_runtime.h>

#define NIN 64
#define NOUT 64
#define NTO 16
#define HH 192
#define WW 192
#define HO 190
#define WO 190
#define WBUF 5120            // per-wave buffer: main 18x16 units + halo 18 units + pad = 320*16B
#define NBLK 2304            // 36 groups (9 tiles x 4 batch) x 64 out channels

__global__ __launch_bounds__(256, 4) void scm_kernel(
    const float* __restrict__ x,
    const float* __restrict__ w,
    const float* __restrict__ bias,
    const int* __restrict__ conn_in,
    float* __restrict__ out)
{
    __shared__ char smem[4 * 2 * WBUF];   // 40960 B: 4 waves x double wave-private buffer

    const int tid  = threadIdx.x;
    const int lane = tid & 63;
    const int tx   = tid & 15;       // col group of 4
    const int ty   = tid >> 4;       // row group of 4 (block-wide)
    const int wv   = ty >> 2;        // wave id 0..3 (rows 16*wv .. +15)
    const int lty  = ty & 3;         // row group within wave

    // XCD-aware swizzle (bijective, 2304 % 8 == 0), o-minor for L2 gather reuse.
    const int lid = (blockIdx.x & 7) * (NBLK / 8) + (blockIdx.x >> 3);
    const int o   = lid & 63;
    const int g   = lid >> 6;        // 0..35
    const int tile = g % 9;
    const int b    = g / 9;
    const int i0 = (tile / 3) * 64;
    const int j0 = (tile % 3) * 64;

    // ---- Wave-private LDS layout per buffer (5120 B), linear unit u = s*64+lane:
    //   u <  288 : main[row u>>4][unit u&15]  -> global (i0+16wv+(u>>4), j0+4*(u&15))
    //   u <  306 : halo[row u-288]            -> global cols j0+64..67
    //   else     : pad (written, never read)
    // Clamped slots feed only outputs >= row/col 190 (discarded).
    int goff[5];
    #pragma unroll
    for (int s = 0; s < 5; ++s) {
        int u = s * 64 + lane;
        int gr, gc;
        if (u < 288)      { int row = u >> 4; gr = i0 + 16 * wv + row; gc = j0 + 4 * (u & 15); }
        else if (u < 306) { int row = u - 288; gr = i0 + 16 * wv + row;
                            gc = j0 + 64; if (gc > 188) gc = 188; }
        else              { gr = 191; gc = 0; }
        if (gr > 191) gr = 191;
        goff[s] = (gr * WW + gc) * 4;
    }

    // Read offsets (channel-independent):
    //   A = float4 cols 4tx..+3  at main[lr][tx]
    //   B = float2 cols 4tx+4,+5 = first 8B of main[lr][tx+1], or halo[lr] for tx=15
    int offA[6], offB[6];
    #pragma unroll
    for (int r = 0; r < 6; ++r) {
        int lr = lty * 4 + r;
        offA[r] = lr * 256 + tx * 16;
        offB[r] = (tx < 15) ? (lr * 256 + (tx + 1) * 16) : (4608 + lr * 16);
    }

    char* wbase = smem + wv * (2 * WBUF);
    char* wdst  = wbase + lane * 16;          // this lane's ds_write slot base
    const char* xb = (const char*)x + (size_t)b * NIN * HH * WW * 4;
    const int kbase = o * NTO;

    float acc[4][4];
    #pragma unroll
    for (int i = 0; i < 4; ++i)
        #pragma unroll
        for (int p = 0; p < 4; ++p) acc[i][p] = 0.f;

    // Staging registers (static names, no runtime indexing).
    float4 s0, s1, s2, s3, s4;

#define GLOAD(t) do {                                                          \
        const int _ci = __builtin_amdgcn_readfirstlane(conn_in[kbase + (t)]);  \
        const char* _src = xb + (size_t)_ci * (HH * WW * 4);                   \
        s0 = *(const float4*)(_src + goff[0]);                                 \
        s1 = *(const float4*)(_src + goff[1]);                                 \
        s2 = *(const float4*)(_src + goff[2]);                                 \
        s3 = *(const float4*)(_src + goff[3]);                                 \
        s4 = *(const float4*)(_src + goff[4]);                                 \
    } while (0)

    GLOAD(0);   // prologue: channel 0 -> regs

    #pragma unroll 1
    for (int t = 0; t < NTO; ++t) {
        const int cur = t & 1;
        char* dst = wdst + cur * WBUF;

        // Write ch t (regs -> LDS). Compiler inserts vmcnt for s0..s4 and
        // lgkm ordering vs our prior reads of this buffer (same-wave, in-order).
        *(float4*)(dst)        = s0;
        *(float4*)(dst + 1024) = s1;
        *(float4*)(dst + 2048) = s2;
        *(float4*)(dst + 3072) = s3;
        *(float4*)(dst + 4096) = s4;

        // Issue ch t+1 global loads immediately; they fly under compute-t.
        if (t < NTO - 1) GLOAD(t + 1);
        __builtin_amdgcn_sched_barrier(0);   // pin: loads issued before compute

        float wv9[9];
        #pragma unroll
        for (int q = 0; q < 9; ++q) wv9[q] = w[(kbase + t) * 9 + q];

        const char* rb = wbase + cur * WBUF;
        #pragma unroll
        for (int r = 0; r < 6; ++r) {
            const float4 v4 = *(const float4*)(rb + offA[r]);
            const float2 v2 = *(const float2*)(rb + offB[r]);
            const float rowv[6] = {v4.x, v4.y, v4.z, v4.w, v2.x, v2.y};
            #pragma unroll
            for (int i = 0; i < 4; ++i) {
                const int kh = r - i;
                if (kh >= 0 && kh < 3) {
                    #pragma unroll
                    for (int kw = 0; kw < 3; ++kw) {
                        const float wk = wv9[kh * 3 + kw];
                        #pragma unroll
                        for (int p = 0; p < 4; ++p)
                            acc[i][p] = fmaf(wk, rowv[p + kw], acc[i][p]);
                    }
                }
            }
        }
    }
#undef GLOAD

    const float bv = bias[o];
    float* outp = out + (size_t)(b * NOUT + o) * (HO * WO);
    #pragma unroll
    for (int i = 0; i < 4; ++i) {
        const int gi = i0 + ty * 4 + i;
        if (gi < HO) {
            const int gj = j0 + tx * 4;
            float* row = outp + (size_t)gi * WO + gj;
            if (gj + 3 < WO) {
                *(float2*)(row)     = make_float2(acc[i][0] + bv, acc[i][1] + bv);
                *(float2*)(row + 2) = make_float2(acc[i][2] + bv, acc[i][3] + bv);
            } else {
                #pragma unroll
                for (int p = 0; p < 4; ++p)
                    if (gj + p < WO) row[p] = acc[i][p] + bv;
            }
        }
    }
}

extern "C" void kernel_launch(void* const* d_in, const int* in_sizes, int n_in,
                              void* d_out, int out_size, void* d_ws, size_t ws_size,
                              hipStream_t stream) {
    const float* x       = (const float*)d_in[0];
    const float* weight  = (const float*)d_in[1];
    const float* bias    = (const float*)d_in[2];
    const int*   conn_in = (const int*)d_in[3];
    // d_in[4] = conn_out (implicit: k -> k/16)

    dim3 grid(NBLK);
    dim3 block(256);
    scm_kernel<<<grid, block, 0, stream>>>(x, weight, bias, conn_in, (float*)d_out);
}

// Round 14
// 54.747 us; speedup vs baseline: 5.4042x; 1.4407x over previous
//
#include <hip/hip_runtime.h>

#define NIN 64
#define NOUT 64
#define NTO 16
#define HH 192
#define WW 192
#define HO 190
#define WO 190
#define WBUF 5120            // per-wave buffer: main 18x16 units + halo 18 units + pad = 320*16B
#define NBLK 2304            // 36 groups (9 tiles x 4 batch) x 64 out channels

typedef const __attribute__((address_space(1))) void gv_t;
typedef __attribute__((address_space(3))) void lv_t;

__global__ __launch_bounds__(256, 4) void scm_kernel(
    const float* __restrict__ x,
    const float* __restrict__ w,
    const float* __restrict__ bias,
    const int* __restrict__ conn_in,
    float* __restrict__ out)
{
    __shared__ char smem[4 * 2 * WBUF];   // 40960 B: 4 waves x (A,B) wave-private buffers

    const int tid  = threadIdx.x;
    const int lane = tid & 63;
    const int tx   = tid & 15;       // col group of 4
    const int ty   = tid >> 4;       // row group of 4 (block-wide)
    const int wv   = ty >> 2;        // wave id 0..3 (rows 16*wv .. +15)
    const int lty  = ty & 3;         // row group within wave

    // XCD-aware swizzle (bijective, 2304 % 8 == 0), o-minor for L2 gather reuse.
    const int lid = (blockIdx.x & 7) * (NBLK / 8) + (blockIdx.x >> 3);
    const int o   = lid & 63;
    const int g   = lid >> 6;        // 0..35
    const int tile = g % 9;
    const int b    = g / 9;
    const int i0 = (tile / 3) * 64;
    const int j0 = (tile % 3) * 64;

    // Wave-private LDS layout per buffer (5120 B), linear unit u = s*64+lane:
    //   u <  288 : main[row u>>4][unit u&15] -> global (i0+16wv+(u>>4), j0+4*(u&15))
    //   u <  306 : halo[row u-288]           -> global cols j0+64..67
    //   else     : pad (written, never read)
    // Clamped slots feed only outputs >= row/col 190 (discarded).
    int goff[5];
    #pragma unroll
    for (int s = 0; s < 5; ++s) {
        int u = s * 64 + lane;
        int gr, gc;
        if (u < 288)      { int row = u >> 4; gr = i0 + 16 * wv + row; gc = j0 + 4 * (u & 15); }
        else if (u < 306) { int row = u - 288; gr = i0 + 16 * wv + row;
                            gc = j0 + 64; if (gc > 188) gc = 188; }
        else              { gr = 191; gc = 0; }
        if (gr > 191) gr = 191;
        goff[s] = (gr * WW + gc) * 4;
    }

    // Read offsets (channel-independent):
    //   A = float4 cols 4tx..+3  at main[lr][tx]
    //   B = float2 cols 4tx+4,+5 = first 8B of main[lr][tx+1], or halo[lr] for tx=15
    int offA[6], offB[6];
    #pragma unroll
    for (int r = 0; r < 6; ++r) {
        int lr = lty * 4 + r;
        offA[r] = lr * 256 + tx * 16;
        offB[r] = (tx < 15) ? (lr * 256 + (tx + 1) * 16) : (4608 + lr * 16);
    }

    char* bufA = smem + wv * (2 * WBUF);
    char* bufB = bufA + WBUF;
    const char* xb = (const char*)x + (size_t)b * NIN * HH * WW * 4;
    const int kbase = o * NTO;

    float acc[4][4];
    #pragma unroll
    for (int i = 0; i < 4; ++i)
        #pragma unroll
        for (int p = 0; p < 4; ++p) acc[i][p] = 0.f;

    // Full-patch read registers (static names).
    float4 p0, p1, p2, p3, p4, p5;
    float2 q0, q1, q2, q3, q4, q5;
    float wv9[9];

#define STAGE(t, lb) do {                                                      \
        const int _ci = __builtin_amdgcn_readfirstlane(conn_in[kbase + (t)]);  \
        const char* _src = xb + (size_t)_ci * (HH * WW * 4);                   \
        _Pragma("unroll")                                                      \
        for (int _s = 0; _s < 5; ++_s)                                         \
            __builtin_amdgcn_global_load_lds((gv_t*)(_src + goff[_s]),         \
                                             (lv_t*)((lb) + _s * 1024),        \
                                             16, 0, 0);                        \
    } while (0)

#define READS(rb) do {                                                         \
        p0 = *(const float4*)((rb) + offA[0]); q0 = *(const float2*)((rb) + offB[0]); \
        p1 = *(const float4*)((rb) + offA[1]); q1 = *(const float2*)((rb) + offB[1]); \
        p2 = *(const float4*)((rb) + offA[2]); q2 = *(const float2*)((rb) + offB[2]); \
        p3 = *(const float4*)((rb) + offA[3]); q3 = *(const float2*)((rb) + offB[3]); \
        p4 = *(const float4*)((rb) + offA[4]); q4 = *(const float2*)((rb) + offB[4]); \
        p5 = *(const float4*)((rb) + offA[5]); q5 = *(const float2*)((rb) + offB[5]); \
    } while (0)

#define ROWF(r, P, Q) do {                                                     \
        const float _rv[6] = {P.x, P.y, P.z, P.w, Q.x, Q.y};                   \
        _Pragma("unroll")                                                      \
        for (int _i = 0; _i < 4; ++_i) {                                       \
            const int _kh = (r) - _i;                                          \
            if (_kh >= 0 && _kh < 3) {                                         \
                _Pragma("unroll")                                              \
                for (int _kw = 0; _kw < 3; ++_kw) {                            \
                    const float _wk = wv9[_kh * 3 + _kw];                      \
                    _Pragma("unroll")                                          \
                    for (int _p = 0; _p < 4; ++_p)                             \
                        acc[_i][_p] = fmaf(_wk, _rv[_p + _kw], acc[_i][_p]);   \
                }                                                              \
            }                                                                  \
        }                                                                      \
    } while (0)

#define ALLROWS() do { ROWF(0,p0,q0); ROWF(1,p1,q1); ROWF(2,p2,q2);            \
                       ROWF(3,p3,q3); ROWF(4,p4,q4); ROWF(5,p5,q5); } while (0)

    // prologue: channels 0,1 in flight
    STAGE(0, bufA);
    STAGE(1, bufB);

    #pragma unroll 1
    for (int tt = 0; tt < 8; ++tt) {
        const int tA = 2 * tt, tB = 2 * tt + 1;

        // ---------- even channel (buffer A) ----------
        #pragma unroll
        for (int q = 0; q < 9; ++q) wv9[q] = w[(kbase + tA) * 9 + q];
        asm volatile("s_waitcnt vmcnt(5)" ::: "memory");   // A's DMA done (B's 5 fly)
        __builtin_amdgcn_sched_barrier(0);
        READS(bufA);                                        // 12 ds_reads back-to-back
        asm volatile("s_waitcnt lgkmcnt(0)" ::: "memory");  // reads landed in regs
        __builtin_amdgcn_sched_barrier(0);
        if (tt < 7) STAGE(tA + 2, bufA);                    // refill A under compute
        ALLROWS();

        // ---------- odd channel (buffer B) ----------
        #pragma unroll
        for (int q = 0; q < 9; ++q) wv9[q] = w[(kbase + tB) * 9 + q];
        if (tt < 7) asm volatile("s_waitcnt vmcnt(5)" ::: "memory");
        else        asm volatile("s_waitcnt vmcnt(0)" ::: "memory");
        __builtin_amdgcn_sched_barrier(0);
        READS(bufB);
        asm volatile("s_waitcnt lgkmcnt(0)" ::: "memory");
        __builtin_amdgcn_sched_barrier(0);
        if (tt < 7) STAGE(tB + 2, bufB);
        ALLROWS();
    }
#undef STAGE
#undef READS
#undef ROWF
#undef ALLROWS

    const float bv = bias[o];
    float* outp = out + (size_t)(b * NOUT + o) * (HO * WO);
    #pragma unroll
    for (int i = 0; i < 4; ++i) {
        const int gi = i0 + ty * 4 + i;
        if (gi < HO) {
            const int gj = j0 + tx * 4;
            float* row = outp + (size_t)gi * WO + gj;
            if (gj + 3 < WO) {
                *(float2*)(row)     = make_float2(acc[i][0] + bv, acc[i][1] + bv);
                *(float2*)(row + 2) = make_float2(acc[i][2] + bv, acc[i][3] + bv);
            } else {
                #pragma unroll
                for (int p = 0; p < 4; ++p)
                    if (gj + p < WO) row[p] = acc[i][p] + bv;
            }
        }
    }
}

extern "C" void kernel_launch(void* const* d_in, const int* in_sizes, int n_in,
                              void* d_out, int out_size, void* d_ws, size_t ws_size,
                              hipStream_t stream) {
    const float* x       = (const float*)d_in[0];
    const float* weight  = (const float*)d_in[1];
    const float* bias    = (const float*)d_in[2];
    const int*   conn_in = (const int*)d_in[3];
    // d_in[4] = conn_out (implicit: k -> k/16)

    dim3 grid(NBLK);
    dim3 block(256);
    scm_kernel<<<grid, block, 0, stream>>>(x, weight, bias, conn_in, (float*)d_out);
}